// Round 19
// baseline (199.257 us; speedup 1.0000x reference)
//
#include <hip/hip_runtime.h>
#include <hip/hip_bf16.h>
#include <cmath>

#define DIM 512
#define HID 256
#define ROWS_PB 64       // rows PER SOURCE per block (tile M = 128 stacked)
#define NCHUNK 16        // K chunks of 32

typedef __attribute__((ext_vector_type(8))) short short8;
typedef __attribute__((ext_vector_type(4))) float f32x4;
typedef __attribute__((ext_vector_type(16))) float f32x16;

#define AS1 __attribute__((address_space(1)))
#define AS3 __attribute__((address_space(3)))

__device__ __forceinline__ unsigned short f2bf(float f) {
  union { float f; unsigned u; } v; v.f = f;
  unsigned u = v.u;
  return (unsigned short)((u + 0x7FFFu + ((u >> 16) & 1u)) >> 16);
}

// Pre-swizzle W1 (fp32 [512,256] row-major) into bf16 fragment order:
// w1s short8-idx kg*256 + col (kg = k>>3). K-chunk c (32 k's) is the
// contiguous 16 KB at byte offset c*16384 — linear global_load_lds staging.
__global__ void w1_swz_kernel(const float* __restrict__ W1,
                              unsigned short* __restrict__ w1s) {
  int tid = blockIdx.x * blockDim.x + threadIdx.x;
  if (tid >= DIM * HID) return;
  int k = tid / HID;
  int c = tid - k * HID;
  w1s[(((k >> 3) * HID) + c) * 8 + (k & 7)] = f2bf(W1[tid]);
}

__device__ __forceinline__ short8 cvt8(const f32x4 p0, const f32x4 p1) {
  short8 r;
  r[0] = (short)f2bf(p0[0]); r[1] = (short)f2bf(p0[1]);
  r[2] = (short)f2bf(p0[2]); r[3] = (short)f2bf(p0[3]);
  r[4] = (short)f2bf(p1[0]); r[5] = (short)f2bf(p1[1]);
  r[6] = (short)f2bf(p1[2]); r[7] = (short)f2bf(p1[3]);
  return r;
}

// One fat GEMM tile per block: M=128 (64 z1 rows + 64 z2 rows stacked),
// N=256, BK=32, 8 waves. Wave w: row-group rg=w&3 (32 stacked rows),
// col-half ch=w>>2 (128 cols); 32x32x16 MFMA, acc = 4 x f32x16.
// A staged fp32 via global_load_lds with 16B-unit XOR swizzle
// (unit' = unit ^ (row&7)) applied on BOTH sides: pre-swizzled global
// source + swizzled LDS read (rule: both-or-neither). B staged linear
// (fragment order is conflict-free). m97 1-barrier-per-chunk double buffer.
// Logits: 32x32 C/D map (verified m101), 32-lane shuffle reduce, col-half
// partials combined in LDS. Epilogue re-reads z from L2-hot lines.
__global__ __launch_bounds__(512, 4) void fa_main_kernel(
    const float* __restrict__ z1, const float* __restrict__ z2,
    const unsigned short* __restrict__ w1s,
    const float* __restrict__ bias1, const float* __restrict__ W2,
    const float* __restrict__ bias2, float* __restrict__ out, int n) {
  // A bufs @0,16384: [128 rows][128 B] fp32 (swizzled units).
  // B bufs @32768,49152: bf16 fragment order. xs @65536: [ch 2][srow 128].
  __shared__ char smem[66560];
  float* xs = (float*)(smem + 65536);

  const int t = threadIdx.x;
  const int w = t >> 6;
  const int l = t & 63;
  const int l31 = l & 31, lhi = l >> 5;
  const int rg = w & 3;   // 32-row group of the stacked 128
  const int ch = w >> 2;  // 128-col half
  const int row0 = blockIdx.x * ROWS_PB;

  // Staging geometry (fixed per thread): stacked row sr = t>>3 (pass0:
  // z1 rows, pass1: z2 rows, same sr), source unit su = (t&7) ^ (sr&7).
  const int sr = t >> 3;
  const int su = (t & 7) ^ (sr & 7);
  const int gclamp = min(row0 + sr, n - 1);
  const float* aSrc0 = z1 + (size_t)gclamp * DIM + (su << 2);
  const float* aSrc1 = z2 + (size_t)gclamp * DIM + (su << 2);

  auto STAGE = [&](int c) {
    char* ad = smem + (c & 1) * 16384;
    char* bd = smem + 32768 + (c & 1) * 16384;
    __builtin_amdgcn_global_load_lds((const AS1 void*)(aSrc0 + (c << 5)),
                                     (AS3 void*)(ad + t * 16), 16, 0, 0);
    __builtin_amdgcn_global_load_lds((const AS1 void*)(aSrc1 + (c << 5)),
                                     (AS3 void*)(ad + 8192 + t * 16), 16, 0,
                                     0);
    const char* bs = (const char*)w1s + c * 16384 + t * 16;
    __builtin_amdgcn_global_load_lds((const AS1 void*)(bs),
                                     (AS3 void*)(bd + t * 16), 16, 0, 0);
    __builtin_amdgcn_global_load_lds((const AS1 void*)(bs + 8192),
                                     (AS3 void*)(bd + 8192 + t * 16), 16, 0,
                                     0);
  };

  STAGE(0);

  f32x16 acc[4];
#pragma unroll
  for (int g = 0; g < 4; ++g)
#pragma unroll
    for (int r = 0; r < 16; ++r) acc[g][r] = 0.f;

  const int R = rg * 32 + l31;  // stacked row this lane computes
  const int rx = R & 7;
  const int aRowByte = R * 128;
  const int bBase = (ch << 7) + l31;

  __syncthreads();  // chunk 0 staged (drains global_load_lds)

  // K-loop: m97 2-phase. STAGE(c+1) into buf^1; read+MFMA on buf; barrier.
#pragma unroll
  for (int c = 0; c < NCHUNK; ++c) {
    if (c + 1 < NCHUNK) STAGE(c + 1);
    __builtin_amdgcn_sched_barrier(0);  // pin stage issue above compute
    const char* ab = smem + (c & 1) * 16384;
    const short8* bb = (const short8*)(smem + 32768 + (c & 1) * 16384);
    // A fragments (fp32 -> bf16): kslice ks, units ug=ks*4+lhi*2, ug+1.
    short8 af0, af1;
    {
      const int ug = (lhi << 1);
      const f32x4 a0 = *(const f32x4*)(ab + aRowByte + ((ug ^ rx) << 4));
      const f32x4 a1 = *(const f32x4*)(ab + aRowByte + (((ug + 1) ^ rx) << 4));
      af0 = cvt8(a0, a1);
    }
    {
      const int ug = 4 + (lhi << 1);
      const f32x4 a0 = *(const f32x4*)(ab + aRowByte + ((ug ^ rx) << 4));
      const f32x4 a1 = *(const f32x4*)(ab + aRowByte + (((ug + 1) ^ rx) << 4));
      af1 = cvt8(a0, a1);
    }
#pragma unroll
    for (int ks = 0; ks < 2; ++ks) {
      const short8 af = ks ? af1 : af0;
      const short8* bp = bb + (((ks << 1) + lhi) << 8) + bBase;
#pragma unroll
      for (int g = 0; g < 4; ++g)
        acc[g] = __builtin_amdgcn_mfma_f32_32x32x16_bf16(af, bp[g << 5],
                                                         acc[g], 0, 0, 0);
    }
    __syncthreads();  // publishes buf^1; protects buf for next overwrite
  }

  // Logits. C/D (32x32): col = ch*128 + g*32 + l31,
  // row-in-group = (r&3) + 8*(r>>2) + 4*lhi (m101-verified).
  float part[16];
#pragma unroll
  for (int r = 0; r < 16; ++r) part[r] = 0.f;
#pragma unroll
  for (int g = 0; g < 4; ++g) {
    const int cc = (ch << 7) + (g << 5) + l31;
    const float w2v = W2[cc];
    const float b1v = bias1[cc];
#pragma unroll
    for (int r = 0; r < 16; ++r) {
      const float hh = acc[g][r] + b1v;
      part[r] += (hh > 0.f) ? hh * w2v : 0.f;
    }
  }
#pragma unroll
  for (int r = 0; r < 16; ++r) {
#pragma unroll
    for (int m = 1; m < 32; m <<= 1) part[r] += __shfl_xor(part[r], m, 64);
  }
  if (l31 == 0) {
#pragma unroll
    for (int r = 0; r < 16; ++r) {
      const int row = (r & 3) + ((r >> 2) << 3) + (lhi << 2);
      xs[(ch << 7) + rg * 32 + row] = part[r];
    }
  }
  __syncthreads();

  // Epilogue: srow 0..63 = z1 logits, 64..127 = z2. Wave w covers output
  // rows w*8..+8; lane l covers cols l*4 and 256+l*4 (z re-read: L2-hot).
#pragma unroll
  for (int j = 0; j < 8; ++j) {
    const int rl = (w << 3) + j;
    const int grow = row0 + rl;
    if (grow < n) {
      const float x = xs[rl] + xs[128 + rl];
      const float y = xs[64 + rl] + xs[192 + rl];
      const float sx = 1.f / (1.f + __expf(y - x));  // b2 cancels
      const float sy = 1.f - sx;
      const size_t off = (size_t)grow * DIM + (l << 2);
#pragma unroll
      for (int half = 0; half < 2; ++half) {
        const size_t o = off + (half << 8);
        const f32x4 a4 = *(const f32x4*)(z1 + o);
        const f32x4 b4 = *(const f32x4*)(z2 + o);
        f32x4 ov;
        ov[0] = sx * a4[0] + sy * b4[0];
        ov[1] = sx * a4[1] + sy * b4[1];
        ov[2] = sx * a4[2] + sy * b4[2];
        ov[3] = sx * a4[3] + sy * b4[3];
        *(f32x4*)(out + o) = ov;
      }
    }
  }
}

extern "C" void kernel_launch(void* const* d_in, const int* in_sizes, int n_in,
                              void* d_out, int out_size, void* d_ws,
                              size_t ws_size, hipStream_t stream) {
  const float* z1 = (const float*)d_in[0];
  const float* z2 = (const float*)d_in[1];
  const float* W1 = (const float*)d_in[2];
  const float* b1 = (const float*)d_in[3];
  const float* W2 = (const float*)d_in[4];
  const float* b2 = (const float*)d_in[5];
  float* out = (float*)d_out;
  const int n = in_sizes[0] / DIM;
  unsigned short* w1s = (unsigned short*)d_ws;  // 512*256*2 = 256 KB

  hipLaunchKernelGGL(w1_swz_kernel, dim3((DIM * HID + 255) / 256), dim3(256),
                     0, stream, W1, w1s);
  const int nwg = (n + ROWS_PB - 1) / ROWS_PB;
  hipLaunchKernelGGL(fa_main_kernel, dim3(nwg), dim3(512), 0, stream, z1, z2,
                     w1s, b1, W2, b2, out, n);
}